// Round 1
// baseline (1075.549 us; speedup 1.0000x reference)
//
#include <hip/hip_runtime.h>
#include <hip/hip_bf16.h>
#include <math.h>

#define D 128
#define NUM_GRAPHS 64

// ---------------- CSR build ----------------

__global__ void k_count(const int* __restrict__ col, int* __restrict__ cnt, int E) {
    int e = blockIdx.x * blockDim.x + threadIdx.x;
    if (e < E) atomicAdd(&cnt[col[e]], 1);
}

// 256 threads, 1024 elements per block: block-local exclusive scan + block sum
__global__ void k_scan1(const int* __restrict__ cnt, int* __restrict__ offs,
                        int* __restrict__ bsum, int N) {
    __shared__ int lds[256];
    int t = threadIdx.x;
    int base = blockIdx.x * 1024 + t * 4;
    int v[4]; int local = 0;
#pragma unroll
    for (int j = 0; j < 4; j++) { v[j] = (base + j < N) ? cnt[base + j] : 0; local += v[j]; }
    lds[t] = local;
    __syncthreads();
    for (int off = 1; off < 256; off <<= 1) {
        int x = (t >= off) ? lds[t - off] : 0;
        __syncthreads();
        lds[t] += x;
        __syncthreads();
    }
    int excl = lds[t] - local;           // exclusive within block
    if (t == 255) bsum[blockIdx.x] = lds[255];
    int run = excl;
#pragma unroll
    for (int j = 0; j < 4; j++) { if (base + j < N) offs[base + j] = run; run += v[j]; }
}

// single block, nb <= 256: exclusive scan of block sums in place
__global__ void k_scan2(int* __restrict__ bsum, int nb) {
    __shared__ int lds[256];
    int t = threadIdx.x;
    int v = (t < nb) ? bsum[t] : 0;
    lds[t] = v;
    __syncthreads();
    for (int off = 1; off < 256; off <<= 1) {
        int x = (t >= off) ? lds[t - off] : 0;
        __syncthreads();
        lds[t] += x;
        __syncthreads();
    }
    if (t < nb) bsum[t] = lds[t] - v;
}

__global__ void k_fixup(const int* __restrict__ cnt, int* __restrict__ offs,
                        const int* __restrict__ bsum, float* __restrict__ dis,
                        int* __restrict__ cursor, int N) {
    int i = blockIdx.x * blockDim.x + threadIdx.x;
    if (i >= N) return;
    int o = offs[i] + bsum[i >> 10];
    offs[i] = o;
    cursor[i] = o;
    dis[i] = rsqrtf(1.0f + (float)cnt[i]);   // deg includes self-loop
}

__global__ void k_fill(const int* __restrict__ ei, int* __restrict__ cursor,
                       const float* __restrict__ dis,
                       int* __restrict__ esrc, float* __restrict__ ew, int E) {
    int e = blockIdx.x * blockDim.x + threadIdx.x;
    if (e >= E) return;
    int r = ei[e];        // source j
    int c = ei[E + e];    // target i
    int pos = atomicAdd(&cursor[c], 1);
    esrc[pos] = r;
    ew[pos] = dis[r];     // dis[target] factored out, applied per-node
}

// ---------------- dense GEMM: Y[N,128] = X[N,128] @ W[128,128] ----------------
// W staged in LDS (64 KB). Wave handles 8 nodes x 128 feats; lane owns f and f+64.
__launch_bounds__(256)
__global__ void k_gemm(const float* __restrict__ X, const float* __restrict__ W,
                       float* __restrict__ Y, int N, int ntiles) {
    __shared__ float sW[D * D];
    for (int i = threadIdx.x; i < D * D; i += 256) sW[i] = W[i];
    __syncthreads();
    int lane = threadIdx.x & 63;
    int wv = threadIdx.x >> 6;          // wave id 0..3
    for (int tile = blockIdx.x; tile < ntiles; tile += gridDim.x) {
        int n0 = tile * 32 + wv * 8;    // this wave's 8 nodes
        float a0[8], a1[8];
#pragma unroll
        for (int j = 0; j < 8; j++) { a0[j] = 0.f; a1[j] = 0.f; }
        // clamp for tail tile: compute garbage on duplicated row, guard the store
        int nn[8];
#pragma unroll
        for (int j = 0; j < 8; j++) nn[j] = (n0 + j < N) ? (n0 + j) : (N - 1);
#pragma unroll 2
        for (int k = 0; k < D; k++) {
            float w0 = sW[k * D + lane];
            float w1 = sW[k * D + 64 + lane];
#pragma unroll
            for (int j = 0; j < 8; j++) {
                float xv = X[(size_t)nn[j] * D + k];   // wave-uniform broadcast load, L1-hot
                a0[j] += xv * w0;
                a1[j] += xv * w1;
            }
        }
#pragma unroll
        for (int j = 0; j < 8; j++) {
            int n = n0 + j;
            if (n < N) {
                Y[(size_t)n * D + lane]      = a0[j];
                Y[(size_t)n * D + 64 + lane] = a1[j];
            }
        }
    }
}

// ---------------- CSR aggregation + bias + leaky ReLU ----------------
// One wave per node; lane owns features (lane, lane+64).
__launch_bounds__(256)
__global__ void k_agg(const float* __restrict__ H, float* __restrict__ O,
                      const int* __restrict__ offs, const int* __restrict__ cnt,
                      const float* __restrict__ dis,
                      const int* __restrict__ esrc, const float* __restrict__ ew,
                      const float* __restrict__ bias, int N) {
    int node = (blockIdx.x * 256 + threadIdx.x) >> 6;
    int lane = threadIdx.x & 63;
    if (node >= N) return;
    int start = offs[node];
    int len = cnt[node];
    float di = dis[node];
    const float* hi = H + (size_t)node * D;
    float acc0 = hi[lane] * di;          // self-loop (x di again at the end -> di^2)
    float acc1 = hi[64 + lane] * di;
    for (int k = 0; k < len; k++) {
        int j = esrc[start + k];
        float w = ew[start + k];
        const float* hj = H + (size_t)j * D;
        acc0 += w * hj[lane];
        acc1 += w * hj[64 + lane];
    }
    acc0 = acc0 * di + bias[lane];
    acc1 = acc1 * di + bias[64 + lane];
    acc0 = acc0 >= 0.f ? acc0 : 0.01f * acc0;
    acc1 = acc1 >= 0.f ? acc1 : 0.01f * acc1;
    O[(size_t)node * D + lane]      = acc0;
    O[(size_t)node * D + 64 + lane] = acc1;
}

// ---------------- pooling: per-graph sums + counts (batch sorted) ----------------
__global__ void k_pool(const float* __restrict__ H, const int* __restrict__ batch,
                       float* __restrict__ pooled, float* __restrict__ gcnt, int N) {
    int f = threadIdx.x;                 // 0..127
    int n0 = blockIdx.x * 128;
    if (n0 >= N) return;
    int n1 = min(n0 + 128, N);
    int cur = batch[n0];
    float acc = 0.f; int run = 0;
    for (int n = n0; n < n1; n++) {
        int g = batch[n];                // uniform across block -> no divergence
        if (g != cur) {
            atomicAdd(&pooled[cur * D + f], acc);
            if (f == 0) atomicAdd(&gcnt[cur], (float)run);
            acc = 0.f; run = 0; cur = g;
        }
        acc += H[(size_t)n * D + f];
        run++;
    }
    atomicAdd(&pooled[cur * D + f], acc);
    if (f == 0) atomicAdd(&gcnt[cur], (float)run);
}

// ---------------- final FC: out[g] = (sum_g . fcW)/max(cnt,1) + fcb ----------------
__global__ void k_fc(const float* __restrict__ pooled, const float* __restrict__ gcnt,
                     const float* __restrict__ fcW, const float* __restrict__ fcb,
                     float* __restrict__ out) {
    __shared__ float red[128];
    int g = blockIdx.x;
    int f = threadIdx.x;
    red[f] = pooled[g * D + f] * fcW[f];
    __syncthreads();
    for (int s = 64; s > 0; s >>= 1) {
        if (f < s) red[f] += red[f + s];
        __syncthreads();
    }
    if (f == 0) out[g] = red[0] / fmaxf(gcnt[g], 1.0f) + fcb[0];
}

extern "C" void kernel_launch(void* const* d_in, const int* in_sizes, int n_in,
                              void* d_out, int out_size, void* d_ws, size_t ws_size,
                              hipStream_t stream) {
    const float* x    = (const float*)d_in[0];
    const int*   ei   = (const int*)d_in[1];
    const int*   batch= (const int*)d_in[2];
    const float* W1   = (const float*)d_in[3];
    const float* b1   = (const float*)d_in[4];
    const float* W2   = (const float*)d_in[5];
    const float* b2   = (const float*)d_in[6];
    const float* fcW  = (const float*)d_in[7];
    const float* fcb  = (const float*)d_in[8];
    float* out = (float*)d_out;

    int N = in_sizes[0] / D;
    int E = in_sizes[1] / 2;

    // workspace bump allocator (256B aligned); total ~118 MB
    char* p = (char*)d_ws;
    auto alloc = [&](size_t bytes) { char* r = p; p += (bytes + 255) & ~(size_t)255; return r; };
    int*   cnt    = (int*)  alloc((size_t)N * 4);
    int*   offs   = (int*)  alloc((size_t)N * 4);
    int*   cursor = (int*)  alloc((size_t)N * 4);
    int*   bsum   = (int*)  alloc(256 * 4);
    float* dis    = (float*)alloc((size_t)N * 4);
    int*   esrc   = (int*)  alloc((size_t)E * 4);
    float* ew     = (float*)alloc((size_t)E * 4);
    float* bufA   = (float*)alloc((size_t)N * D * 4);
    float* bufB   = (float*)alloc((size_t)N * D * 4);
    float* pooled = (float*)alloc((size_t)NUM_GRAPHS * D * 4);
    float* gcnt   = (float*)alloc((size_t)NUM_GRAPHS * 4);

    hipMemsetAsync(cnt, 0, (size_t)N * 4, stream);
    hipMemsetAsync(pooled, 0, (size_t)NUM_GRAPHS * D * 4, stream);
    hipMemsetAsync(gcnt, 0, (size_t)NUM_GRAPHS * 4, stream);

    int eb = (E + 255) / 256;
    int nb = (N + 1023) / 1024;

    k_count<<<eb, 256, 0, stream>>>(ei + E, cnt, E);
    k_scan1<<<nb, 256, 0, stream>>>(cnt, offs, bsum, N);
    k_scan2<<<1, 256, 0, stream>>>(bsum, nb);
    k_fixup<<<(N + 255) / 256, 256, 0, stream>>>(cnt, offs, bsum, dis, cursor, N);
    k_fill<<<eb, 256, 0, stream>>>(ei, cursor, dis, esrc, ew, E);

    int ntiles = (N + 31) / 32;
    int gblocks = ntiles < 1024 ? ntiles : 1024;

    // layer 1: bufA = x@W1 ; bufB = leaky(agg(bufA) + b1)
    k_gemm<<<gblocks, 256, 0, stream>>>(x, W1, bufA, N, ntiles);
    k_agg<<<(N + 3) / 4, 256, 0, stream>>>(bufA, bufB, offs, cnt, dis, esrc, ew, b1, N);
    // layer 2: bufA = bufB@W2 ; bufB = leaky(agg(bufA) + b2)
    k_gemm<<<gblocks, 256, 0, stream>>>(bufB, W2, bufA, N, ntiles);
    k_agg<<<(N + 3) / 4, 256, 0, stream>>>(bufA, bufB, offs, cnt, dis, esrc, ew, b2, N);
    // pool + fc
    k_pool<<<(N + 127) / 128, 128, 0, stream>>>(bufB, batch, pooled, gcnt, N);
    k_fc<<<NUM_GRAPHS, 128, 0, stream>>>(pooled, gcnt, fcW, fcb, out);
}

// Round 2
// 667.088 us; speedup vs baseline: 1.6123x; 1.6123x over previous
//
#include <hip/hip_runtime.h>
#include <hip/hip_bf16.h>
#include <math.h>

#define D 128
#define NUM_GRAPHS 64

// ---------------- CSR build ----------------

__global__ void k_count(const int* __restrict__ col, int* __restrict__ cnt, int E) {
    int e = blockIdx.x * blockDim.x + threadIdx.x;
    if (e < E) atomicAdd(&cnt[col[e]], 1);
}

// 256 threads, 1024 elements per block: block-local exclusive scan + block sum
__global__ void k_scan1(const int* __restrict__ cnt, int* __restrict__ offs,
                        int* __restrict__ bsum, int N) {
    __shared__ int lds[256];
    int t = threadIdx.x;
    int base = blockIdx.x * 1024 + t * 4;
    int v[4]; int local = 0;
#pragma unroll
    for (int j = 0; j < 4; j++) { v[j] = (base + j < N) ? cnt[base + j] : 0; local += v[j]; }
    lds[t] = local;
    __syncthreads();
    for (int off = 1; off < 256; off <<= 1) {
        int x = (t >= off) ? lds[t - off] : 0;
        __syncthreads();
        lds[t] += x;
        __syncthreads();
    }
    int excl = lds[t] - local;
    if (t == 255) bsum[blockIdx.x] = lds[255];
    int run = excl;
#pragma unroll
    for (int j = 0; j < 4; j++) { if (base + j < N) offs[base + j] = run; run += v[j]; }
}

__global__ void k_scan2(int* __restrict__ bsum, int nb) {
    __shared__ int lds[256];
    int t = threadIdx.x;
    int v = (t < nb) ? bsum[t] : 0;
    lds[t] = v;
    __syncthreads();
    for (int off = 1; off < 256; off <<= 1) {
        int x = (t >= off) ? lds[t - off] : 0;
        __syncthreads();
        lds[t] += x;
        __syncthreads();
    }
    if (t < nb) bsum[t] = lds[t] - v;
}

__global__ void k_fixup(const int* __restrict__ cnt, int* __restrict__ offs,
                        const int* __restrict__ bsum, float* __restrict__ dis,
                        int* __restrict__ cursor, int N) {
    int i = blockIdx.x * blockDim.x + threadIdx.x;
    if (i >= N) return;
    int o = offs[i] + bsum[i >> 10];
    offs[i] = o;
    cursor[i] = o;
    dis[i] = rsqrtf(1.0f + (float)cnt[i]);   // deg includes self-loop
}

// pack (src, dis[src]) into one 8B record
__global__ void k_fill(const int* __restrict__ ei, int* __restrict__ cursor,
                       const float* __restrict__ dis,
                       int2* __restrict__ epack, int E) {
    int e = blockIdx.x * blockDim.x + threadIdx.x;
    if (e >= E) return;
    int r = ei[e];        // source j
    int c = ei[E + e];    // target i
    int pos = atomicAdd(&cursor[c], 1);
    int2 p; p.x = r; p.y = __float_as_int(dis[r]);
    epack[pos] = p;
}

// ---------------- W transpose: WT[f][k] = W[k][f] ----------------
__global__ void k_transpose(const float* __restrict__ W, float* __restrict__ WT) {
    int idx = blockIdx.x * 256 + threadIdx.x;   // 0..16383
    int k = idx >> 7, f = idx & 127;
    WT[f * D + k] = W[idx];
}

// ---------------- dense GEMM: Y[N,128] = X[N,128] @ W[128,128] ----------------
// Block = 256 threads, computes 64 nodes x 64 features (blockIdx.y picks f-half).
// Whole K=128 staged once: sX[64][128], sW(T-half)[64][128], XOR-swizzled 16B
// granules instead of padding -> exactly 64 KB LDS, 2 blocks/CU.
// Thread (tf=tid&15, tn=tid>>4) computes nodes {tn+16i}, feats {tf+16j}.
__launch_bounds__(256, 2)
__global__ void k_gemm(const float* __restrict__ X, const float* __restrict__ WT,
                       float* __restrict__ Y, int N) {
    __shared__ float sX[64 * D];
    __shared__ float sW[64 * D];
    int tid = threadIdx.x;
    int n0 = blockIdx.x * 64;
    int f0 = blockIdx.y * 64;

    // stage: 8 passes, each thread one float4 per array per pass
    {
        int c4 = (tid & 31) * 4;       // word offset in row (16B granule)
        int r  = tid >> 5;             // 0..7 ; row = pass*8 + r, row&7 == r
        int sw = (r & 7) * 4;          // swizzle words
        int cs = c4 ^ sw;              // swizzled word offset
#pragma unroll
        for (int pass = 0; pass < 8; pass++) {
            int row = pass * 8 + r;
            int gn = n0 + row;
            int gnc = gn < N ? gn : N - 1;
            float4 xv = *(const float4*)(X  + (size_t)gnc * D + c4);
            *(float4*)(&sX[row * D + cs]) = xv;
            float4 wv = *(const float4*)(WT + (size_t)(f0 + row) * D + c4);
            *(float4*)(&sW[row * D + cs]) = wv;
        }
    }
    __syncthreads();

    int tf = tid & 15;
    int tn = tid >> 4;
    int swx = (tn & 7) * 4;
    int sww = (tf & 7) * 4;
    float acc[4][4];
#pragma unroll
    for (int i = 0; i < 4; i++)
#pragma unroll
        for (int j = 0; j < 4; j++) acc[i][j] = 0.f;

#pragma unroll 2
    for (int k = 0; k < D; k += 4) {
        int kx = k ^ swx;
        int kw = k ^ sww;
        float4 a[4], b[4];
#pragma unroll
        for (int i = 0; i < 4; i++) a[i] = *(const float4*)(&sX[(tn + 16 * i) * D + kx]);
#pragma unroll
        for (int j = 0; j < 4; j++) b[j] = *(const float4*)(&sW[(tf + 16 * j) * D + kw]);
#pragma unroll
        for (int i = 0; i < 4; i++)
#pragma unroll
            for (int j = 0; j < 4; j++)
                acc[i][j] += a[i].x * b[j].x + a[i].y * b[j].y
                           + a[i].z * b[j].z + a[i].w * b[j].w;
    }

#pragma unroll
    for (int i = 0; i < 4; i++) {
        int n = n0 + tn + 16 * i;
        if (n < N) {
#pragma unroll
            for (int j = 0; j < 4; j++)
                Y[(size_t)n * D + f0 + tf + 16 * j] = acc[i][j];
        }
    }
}

// ---------------- CSR aggregation + bias + leaky ReLU ----------------
// One wave per node; lane owns feats (2*lane, 2*lane+1) as float2.
// Edge metadata preloaded 64-at-a-time via coalesced int2 load + shfl broadcast;
// gather loop unrolled x4 for 4 outstanding 512B row-gathers per wave.
__launch_bounds__(256)
__global__ void k_agg(const float* __restrict__ H, float* __restrict__ O,
                      const int* __restrict__ offs, const int* __restrict__ cnt,
                      const float* __restrict__ dis, const int2* __restrict__ epack,
                      const float* __restrict__ bias, int N) {
    int node = (blockIdx.x * 256 + threadIdx.x) >> 6;
    int lane = threadIdx.x & 63;
    if (node >= N) return;
    int start = offs[node];
    int len = cnt[node];
    float di = dis[node];
    float2 h = *(const float2*)(H + (size_t)node * D + lane * 2);
    float acc0 = h.x * di;           // self-loop (times di again at end -> di^2)
    float acc1 = h.y * di;

    for (int k0 = 0; k0 < len; k0 += 64) {
        int m = len - k0; if (m > 64) m = 64;
        int2 ep = epack[start + k0 + (lane < m ? lane : 0)];
        float epw = __int_as_float(ep.y);
        int j = 0;
        for (; j + 4 <= m; j += 4) {
            int s0 = __shfl(ep.x, j + 0), s1 = __shfl(ep.x, j + 1);
            int s2 = __shfl(ep.x, j + 2), s3 = __shfl(ep.x, j + 3);
            float w0 = __shfl(epw, j + 0), w1 = __shfl(epw, j + 1);
            float w2 = __shfl(epw, j + 2), w3 = __shfl(epw, j + 3);
            float2 h0 = *(const float2*)(H + (size_t)s0 * D + lane * 2);
            float2 h1 = *(const float2*)(H + (size_t)s1 * D + lane * 2);
            float2 h2 = *(const float2*)(H + (size_t)s2 * D + lane * 2);
            float2 h3 = *(const float2*)(H + (size_t)s3 * D + lane * 2);
            acc0 += w0 * h0.x; acc1 += w0 * h0.y;
            acc0 += w1 * h1.x; acc1 += w1 * h1.y;
            acc0 += w2 * h2.x; acc1 += w2 * h2.y;
            acc0 += w3 * h3.x; acc1 += w3 * h3.y;
        }
        for (; j < m; j++) {
            int s = __shfl(ep.x, j);
            float w = __shfl(epw, j);
            float2 hj = *(const float2*)(H + (size_t)s * D + lane * 2);
            acc0 += w * hj.x; acc1 += w * hj.y;
        }
    }

    float b0 = bias[lane * 2], b1 = bias[lane * 2 + 1];
    acc0 = acc0 * di + b0;
    acc1 = acc1 * di + b1;
    acc0 = acc0 >= 0.f ? acc0 : 0.01f * acc0;
    acc1 = acc1 >= 0.f ? acc1 : 0.01f * acc1;
    float2 o; o.x = acc0; o.y = acc1;
    *(float2*)(O + (size_t)node * D + lane * 2) = o;
}

// ---------------- pooling: per-graph sums + counts (batch sorted) ----------------
__global__ void k_pool(const float* __restrict__ H, const int* __restrict__ batch,
                       float* __restrict__ pooled, float* __restrict__ gcnt, int N) {
    int f = threadIdx.x;                 // 0..127
    int n0 = blockIdx.x * 128;
    if (n0 >= N) return;
    int n1 = min(n0 + 128, N);
    int cur = batch[n0];
    float acc = 0.f; int run = 0;
    for (int n = n0; n < n1; n++) {
        int g = batch[n];                // uniform across block -> no divergence
        if (g != cur) {
            atomicAdd(&pooled[cur * D + f], acc);
            if (f == 0) atomicAdd(&gcnt[cur], (float)run);
            acc = 0.f; run = 0; cur = g;
        }
        acc += H[(size_t)n * D + f];
        run++;
    }
    atomicAdd(&pooled[cur * D + f], acc);
    if (f == 0) atomicAdd(&gcnt[cur], (float)run);
}

// ---------------- final FC ----------------
__global__ void k_fc(const float* __restrict__ pooled, const float* __restrict__ gcnt,
                     const float* __restrict__ fcW, const float* __restrict__ fcb,
                     float* __restrict__ out) {
    __shared__ float red[128];
    int g = blockIdx.x;
    int f = threadIdx.x;
    red[f] = pooled[g * D + f] * fcW[f];
    __syncthreads();
    for (int s = 64; s > 0; s >>= 1) {
        if (f < s) red[f] += red[f + s];
        __syncthreads();
    }
    if (f == 0) out[g] = red[0] / fmaxf(gcnt[g], 1.0f) + fcb[0];
}

extern "C" void kernel_launch(void* const* d_in, const int* in_sizes, int n_in,
                              void* d_out, int out_size, void* d_ws, size_t ws_size,
                              hipStream_t stream) {
    const float* x    = (const float*)d_in[0];
    const int*   ei   = (const int*)d_in[1];
    const int*   batch= (const int*)d_in[2];
    const float* W1   = (const float*)d_in[3];
    const float* b1   = (const float*)d_in[4];
    const float* W2   = (const float*)d_in[5];
    const float* b2   = (const float*)d_in[6];
    const float* fcW  = (const float*)d_in[7];
    const float* fcb  = (const float*)d_in[8];
    float* out = (float*)d_out;

    int N = in_sizes[0] / D;
    int E = in_sizes[1] / 2;

    char* p = (char*)d_ws;
    auto alloc = [&](size_t bytes) { char* r = p; p += (bytes + 255) & ~(size_t)255; return r; };
    int*   cnt    = (int*)  alloc((size_t)N * 4);
    int*   offs   = (int*)  alloc((size_t)N * 4);
    int*   cursor = (int*)  alloc((size_t)N * 4);
    int*   bsum   = (int*)  alloc(256 * 4);
    float* dis    = (float*)alloc((size_t)N * 4);
    int2*  epack  = (int2*) alloc((size_t)E * 8);
    float* bufA   = (float*)alloc((size_t)N * D * 4);
    float* bufB   = (float*)alloc((size_t)N * D * 4);
    float* WT1    = (float*)alloc((size_t)D * D * 4);
    float* WT2    = (float*)alloc((size_t)D * D * 4);
    float* pooled = (float*)alloc((size_t)NUM_GRAPHS * D * 4);
    float* gcnt   = (float*)alloc((size_t)NUM_GRAPHS * 4);

    hipMemsetAsync(cnt, 0, (size_t)N * 4, stream);
    hipMemsetAsync(pooled, 0, (size_t)NUM_GRAPHS * D * 4, stream);
    hipMemsetAsync(gcnt, 0, (size_t)NUM_GRAPHS * 4, stream);

    int eb = (E + 255) / 256;
    int nb = (N + 1023) / 1024;

    k_count<<<eb, 256, 0, stream>>>(ei + E, cnt, E);
    k_scan1<<<nb, 256, 0, stream>>>(cnt, offs, bsum, N);
    k_scan2<<<1, 256, 0, stream>>>(bsum, nb);
    k_fixup<<<(N + 255) / 256, 256, 0, stream>>>(cnt, offs, bsum, dis, cursor, N);
    k_fill<<<eb, 256, 0, stream>>>(ei, cursor, dis, epack, E);
    k_transpose<<<64, 256, 0, stream>>>(W1, WT1);
    k_transpose<<<64, 256, 0, stream>>>(W2, WT2);

    dim3 ggrid((N + 63) / 64, 2);

    // layer 1
    k_gemm<<<ggrid, 256, 0, stream>>>(x, WT1, bufA, N);
    k_agg<<<(N + 3) / 4, 256, 0, stream>>>(bufA, bufB, offs, cnt, dis, epack, b1, N);
    // layer 2
    k_gemm<<<ggrid, 256, 0, stream>>>(bufB, WT2, bufA, N);
    k_agg<<<(N + 3) / 4, 256, 0, stream>>>(bufA, bufB, offs, cnt, dis, epack, b2, N);
    // pool + fc
    k_pool<<<(N + 127) / 128, 128, 0, stream>>>(bufB, batch, pooled, gcnt, N);
    k_fc<<<NUM_GRAPHS, 128, 0, stream>>>(pooled, gcnt, fcW, fcb, out);
}

// Round 3
// 482.612 us; speedup vs baseline: 2.2286x; 1.3822x over previous
//
#include <hip/hip_runtime.h>
#include <hip/hip_bf16.h>
#include <math.h>

#define D 128
#define NUM_GRAPHS 64

typedef __bf16 bf16x8 __attribute__((ext_vector_type(8)));
typedef __bf16 bf16x2 __attribute__((ext_vector_type(2)));
typedef float f32x4 __attribute__((ext_vector_type(4)));

// ---------------- CSR build ----------------

__global__ void k_count(const int* __restrict__ col, int* __restrict__ cnt, int E) {
    int e = blockIdx.x * blockDim.x + threadIdx.x;
    if (e < E) atomicAdd(&cnt[col[e]], 1);
}

__global__ void k_scan1(const int* __restrict__ cnt, int* __restrict__ offs,
                        int* __restrict__ bsum, int N) {
    __shared__ int lds[256];
    int t = threadIdx.x;
    int base = blockIdx.x * 1024 + t * 4;
    int v[4]; int local = 0;
#pragma unroll
    for (int j = 0; j < 4; j++) { v[j] = (base + j < N) ? cnt[base + j] : 0; local += v[j]; }
    lds[t] = local;
    __syncthreads();
    for (int off = 1; off < 256; off <<= 1) {
        int x = (t >= off) ? lds[t - off] : 0;
        __syncthreads();
        lds[t] += x;
        __syncthreads();
    }
    int excl = lds[t] - local;
    if (t == 255) bsum[blockIdx.x] = lds[255];
    int run = excl;
#pragma unroll
    for (int j = 0; j < 4; j++) { if (base + j < N) offs[base + j] = run; run += v[j]; }
}

__global__ void k_scan2(int* __restrict__ bsum, int nb) {
    __shared__ int lds[256];
    int t = threadIdx.x;
    int v = (t < nb) ? bsum[t] : 0;
    lds[t] = v;
    __syncthreads();
    for (int off = 1; off < 256; off <<= 1) {
        int x = (t >= off) ? lds[t - off] : 0;
        __syncthreads();
        lds[t] += x;
        __syncthreads();
    }
    if (t < nb) bsum[t] = lds[t] - v;
}

__global__ void k_fixup(const int* __restrict__ cnt, int* __restrict__ offs,
                        const int* __restrict__ bsum, float* __restrict__ dis,
                        int* __restrict__ cursor, int N) {
    int i = blockIdx.x * blockDim.x + threadIdx.x;
    if (i >= N) return;
    int o = offs[i] + bsum[i >> 10];
    offs[i] = o;
    cursor[i] = o;
    dis[i] = rsqrtf(1.0f + (float)cnt[i]);   // deg includes self-loop
}

__global__ void k_fill(const int* __restrict__ ei, int* __restrict__ cursor,
                       const float* __restrict__ dis,
                       int2* __restrict__ epack, int E) {
    int e = blockIdx.x * blockDim.x + threadIdx.x;
    if (e >= E) return;
    int r = ei[e];        // source j
    int c = ei[E + e];    // target i
    int pos = atomicAdd(&cursor[c], 1);
    int2 p; p.x = r; p.y = __float_as_int(dis[r]);
    epack[pos] = p;
}

// ---------------- W -> bf16 B-fragment pack ----------------
// Wfrag[ft(8)][kc(4)][lane(64)][j(8)] = bf16( W[kc*32 + (lane>>4)*8 + j][ft*16 + (lane&15)] )
// so one 16B load per (ft,kc) gives the exact mfma_f32_16x16x32_bf16 B-operand.
__global__ void k_prepW(const float* __restrict__ W, __bf16* __restrict__ Wfrag) {
    int idx = blockIdx.x * 256 + threadIdx.x;   // 0..16383
    int j = idx & 7, lane = (idx >> 3) & 63, kc = (idx >> 9) & 3, ft = idx >> 11;
    int k = kc * 32 + (lane >> 4) * 8 + j;
    int f = ft * 16 + (lane & 15);
    Wfrag[idx] = (__bf16)W[k * D + f];
}

// ---------------- MFMA GEMM: Y[N,128](bf16) = X[N,128] @ W ----------------
// 256 thr = 4 waves; wave handles 16 nodes x 128 feats = 8 tiles of 16x16, K=128.
// A-frags straight from global (nodes contiguous -> L1-friendly); B-frags from
// L1-hot 32KB Wfrag. No LDS, no barriers.
template <typename T>
__launch_bounds__(256)
__global__ void k_gemm(const T* __restrict__ X, const __bf16* __restrict__ Wfrag,
                       __bf16* __restrict__ Y, int N) {
    int tid = threadIdx.x;
    int w = tid >> 6, lane = tid & 63;
    int quad = lane >> 4, m = lane & 15;
    int nodeA = blockIdx.x * 64 + w * 16 + m;          // row this lane's A-frag covers
    if (nodeA >= N) nodeA = N - 1;                      // clamp; stores guarded below

    bf16x8 a[4];
#pragma unroll
    for (int kc = 0; kc < 4; kc++) {
        int kb = kc * 32 + quad * 8;
        if constexpr (sizeof(T) == 4) {
            f32x4 x0 = *(const f32x4*)(X + (size_t)nodeA * D + kb);
            f32x4 x1 = *(const f32x4*)(X + (size_t)nodeA * D + kb + 4);
#pragma unroll
            for (int j = 0; j < 4; j++) { a[kc][j] = (__bf16)x0[j]; a[kc][4 + j] = (__bf16)x1[j]; }
        } else {
            a[kc] = *(const bf16x8*)(X + (size_t)nodeA * D + kb);
        }
    }

    f32x4 d[8];
#pragma unroll
    for (int ft = 0; ft < 8; ft++) {
        d[ft] = (f32x4){0.f, 0.f, 0.f, 0.f};
#pragma unroll
        for (int kc = 0; kc < 4; kc++) {
            bf16x8 b = *(const bf16x8*)(Wfrag + (((ft << 2) | kc) * 64 + lane) * 8);
            d[ft] = __builtin_amdgcn_mfma_f32_16x16x32_bf16(a[kc], b, d[ft], 0, 0, 0);
        }
    }

    // C/D layout: col(lane&15)=feature, row=quad*4+reg = node-within-16
#pragma unroll
    for (int r = 0; r < 4; r++) {
        int node = blockIdx.x * 64 + w * 16 + quad * 4 + r;
        if (node < N) {
#pragma unroll
            for (int ft = 0; ft < 8; ft++)
                Y[(size_t)node * D + ft * 16 + m] = (__bf16)d[ft][r];
        }
    }
}

// ---------------- CSR aggregation + bias + leaky ReLU (bf16 in/out) ----------------
// One wave per node; lane owns feats (2*lane, 2*lane+1). Edge meta preloaded
// 64-at-a-time (coalesced int2 + shfl broadcast); gather unrolled x8.
__launch_bounds__(256)
__global__ void k_agg(const __bf16* __restrict__ H, __bf16* __restrict__ O,
                      const int* __restrict__ offs, const int* __restrict__ cnt,
                      const float* __restrict__ dis, const int2* __restrict__ epack,
                      const float* __restrict__ bias, int N) {
    int node = (blockIdx.x * 256 + threadIdx.x) >> 6;
    int lane = threadIdx.x & 63;
    if (node >= N) return;
    int start = offs[node];
    int len = cnt[node];
    float di = dis[node];
    bf16x2 h = *(const bf16x2*)(H + (size_t)node * D + lane * 2);
    float acc0 = (float)h[0] * di;       // self-loop (x di again at end -> di^2)
    float acc1 = (float)h[1] * di;

    for (int k0 = 0; k0 < len; k0 += 64) {
        int mm = len - k0; if (mm > 64) mm = 64;
        int2 ep = epack[start + k0 + (lane < mm ? lane : 0)];
        float epw = __int_as_float(ep.y);
        int j = 0;
        for (; j + 8 <= mm; j += 8) {
            int s[8]; float w[8]; bf16x2 hv[8];
#pragma unroll
            for (int u = 0; u < 8; u++) { s[u] = __shfl(ep.x, j + u); w[u] = __shfl(epw, j + u); }
#pragma unroll
            for (int u = 0; u < 8; u++) hv[u] = *(const bf16x2*)(H + (size_t)s[u] * D + lane * 2);
#pragma unroll
            for (int u = 0; u < 8; u++) { acc0 += w[u] * (float)hv[u][0]; acc1 += w[u] * (float)hv[u][1]; }
        }
        for (; j < mm; j++) {
            int s = __shfl(ep.x, j);
            float w = __shfl(epw, j);
            bf16x2 hv = *(const bf16x2*)(H + (size_t)s * D + lane * 2);
            acc0 += w * (float)hv[0]; acc1 += w * (float)hv[1];
        }
    }

    acc0 = acc0 * di + bias[lane * 2];
    acc1 = acc1 * di + bias[lane * 2 + 1];
    acc0 = acc0 >= 0.f ? acc0 : 0.01f * acc0;
    acc1 = acc1 >= 0.f ? acc1 : 0.01f * acc1;
    bf16x2 o; o[0] = (__bf16)acc0; o[1] = (__bf16)acc1;
    *(bf16x2*)(O + (size_t)node * D + lane * 2) = o;
}

// ---------------- pooling (bf16 in, fp32 accum) ----------------
__global__ void k_pool(const __bf16* __restrict__ H, const int* __restrict__ batch,
                       float* __restrict__ pooled, float* __restrict__ gcnt, int N) {
    int f = threadIdx.x;                 // 0..127
    int n0 = blockIdx.x * 128;
    if (n0 >= N) return;
    int n1 = min(n0 + 128, N);
    int cur = batch[n0];
    float acc = 0.f; int run = 0;
    for (int n = n0; n < n1; n++) {
        int g = batch[n];                // uniform across block -> no divergence
        if (g != cur) {
            atomicAdd(&pooled[cur * D + f], acc);
            if (f == 0) atomicAdd(&gcnt[cur], (float)run);
            acc = 0.f; run = 0; cur = g;
        }
        acc += (float)H[(size_t)n * D + f];
        run++;
    }
    atomicAdd(&pooled[cur * D + f], acc);
    if (f == 0) atomicAdd(&gcnt[cur], (float)run);
}

// ---------------- final FC ----------------
__global__ void k_fc(const float* __restrict__ pooled, const float* __restrict__ gcnt,
                     const float* __restrict__ fcW, const float* __restrict__ fcb,
                     float* __restrict__ out) {
    __shared__ float red[128];
    int g = blockIdx.x;
    int f = threadIdx.x;
    red[f] = pooled[g * D + f] * fcW[f];
    __syncthreads();
    for (int s = 64; s > 0; s >>= 1) {
        if (f < s) red[f] += red[f + s];
        __syncthreads();
    }
    if (f == 0) out[g] = red[0] / fmaxf(gcnt[g], 1.0f) + fcb[0];
}

extern "C" void kernel_launch(void* const* d_in, const int* in_sizes, int n_in,
                              void* d_out, int out_size, void* d_ws, size_t ws_size,
                              hipStream_t stream) {
    const float* x    = (const float*)d_in[0];
    const int*   ei   = (const int*)d_in[1];
    const int*   batch= (const int*)d_in[2];
    const float* W1   = (const float*)d_in[3];
    const float* b1   = (const float*)d_in[4];
    const float* W2   = (const float*)d_in[5];
    const float* b2   = (const float*)d_in[6];
    const float* fcW  = (const float*)d_in[7];
    const float* fcb  = (const float*)d_in[8];
    float* out = (float*)d_out;

    int N = in_sizes[0] / D;
    int E = in_sizes[1] / 2;

    char* p = (char*)d_ws;
    auto alloc = [&](size_t bytes) { char* r = p; p += (bytes + 255) & ~(size_t)255; return r; };
    int*    cnt    = (int*)   alloc((size_t)N * 4);
    int*    offs   = (int*)   alloc((size_t)N * 4);
    int*    cursor = (int*)   alloc((size_t)N * 4);
    int*    bsum   = (int*)   alloc(256 * 4);
    float*  dis    = (float*) alloc((size_t)N * 4);
    int2*   epack  = (int2*)  alloc((size_t)E * 8);
    __bf16* bufA   = (__bf16*)alloc((size_t)N * D * 2);
    __bf16* bufB   = (__bf16*)alloc((size_t)N * D * 2);
    __bf16* Wf1    = (__bf16*)alloc((size_t)D * D * 2);
    __bf16* Wf2    = (__bf16*)alloc((size_t)D * D * 2);
    float*  pooled = (float*) alloc((size_t)NUM_GRAPHS * D * 4);
    float*  gcnt   = (float*) alloc((size_t)NUM_GRAPHS * 4);

    hipMemsetAsync(cnt, 0, (size_t)N * 4, stream);
    hipMemsetAsync(pooled, 0, (size_t)NUM_GRAPHS * D * 4, stream);
    hipMemsetAsync(gcnt, 0, (size_t)NUM_GRAPHS * 4, stream);

    int eb = (E + 255) / 256;
    int nb = (N + 1023) / 1024;

    k_count<<<eb, 256, 0, stream>>>(ei + E, cnt, E);
    k_scan1<<<nb, 256, 0, stream>>>(cnt, offs, bsum, N);
    k_scan2<<<1, 256, 0, stream>>>(bsum, nb);
    k_fixup<<<(N + 255) / 256, 256, 0, stream>>>(cnt, offs, bsum, dis, cursor, N);
    k_fill<<<eb, 256, 0, stream>>>(ei, cursor, dis, epack, E);
    k_prepW<<<64, 256, 0, stream>>>(W1, Wf1);
    k_prepW<<<64, 256, 0, stream>>>(W2, Wf2);

    int gblocks = (N + 63) / 64;

    // layer 1
    k_gemm<float><<<gblocks, 256, 0, stream>>>(x, Wf1, bufA, N);
    k_agg<<<(N + 3) / 4, 256, 0, stream>>>(bufA, bufB, offs, cnt, dis, epack, b1, N);
    // layer 2
    k_gemm<__bf16><<<gblocks, 256, 0, stream>>>(bufB, Wf2, bufA, N);
    k_agg<<<(N + 3) / 4, 256, 0, stream>>>(bufA, bufB, offs, cnt, dis, epack, b2, N);
    // pool + fc
    k_pool<<<(N + 127) / 128, 128, 0, stream>>>(bufB, batch, pooled, gcnt, N);
    k_fc<<<NUM_GRAPHS, 128, 0, stream>>>(pooled, gcnt, fcW, fcb, out);
}

// Round 4
// 396.762 us; speedup vs baseline: 2.7108x; 1.2164x over previous
//
#include <hip/hip_runtime.h>
#include <hip/hip_bf16.h>
#include <math.h>

#define D 128
#define NUM_GRAPHS 64
#define CHUNK 8192          // edges per binning block

typedef __bf16 bf16x8 __attribute__((ext_vector_type(8)));
typedef __bf16 bf16x2 __attribute__((ext_vector_type(2)));
typedef float f32x4 __attribute__((ext_vector_type(4)));

// ---------------- generic scan helpers ----------------
// 256 threads, 1024 elements per block: block-local exclusive scan + block sum
__global__ void k_scan1(const int* __restrict__ in, int* __restrict__ outv,
                        int* __restrict__ bsum, int N) {
    __shared__ int lds[256];
    int t = threadIdx.x;
    int base = blockIdx.x * 1024 + t * 4;
    int v[4]; int local = 0;
#pragma unroll
    for (int j = 0; j < 4; j++) { v[j] = (base + j < N) ? in[base + j] : 0; local += v[j]; }
    lds[t] = local;
    __syncthreads();
    for (int off = 1; off < 256; off <<= 1) {
        int x = (t >= off) ? lds[t - off] : 0;
        __syncthreads();
        lds[t] += x;
        __syncthreads();
    }
    int excl = lds[t] - local;
    if (t == 255) bsum[blockIdx.x] = lds[255];
    int run = excl;
#pragma unroll
    for (int j = 0; j < 4; j++) { if (base + j < N) outv[base + j] = run; run += v[j]; }
}

__global__ void k_scan2(int* __restrict__ bsum, int nb) {
    __shared__ int lds[256];
    int t = threadIdx.x;
    int v = (t < nb) ? bsum[t] : 0;
    lds[t] = v;
    __syncthreads();
    for (int off = 1; off < 256; off <<= 1) {
        int x = (t >= off) ? lds[t - off] : 0;
        __syncthreads();
        lds[t] += x;
        __syncthreads();
    }
    if (t < nb) bsum[t] = lds[t] - v;
}

// ---------------- CSR build: two-level counting sort ----------------
// pass 1: per-chunk histogram over coarse buckets (col>>8)
__global__ void k_hist(const int* __restrict__ col, int* __restrict__ hist,
                       int nbuck, int nchunk, int E) {
    __shared__ int h[512];
    int tid = threadIdx.x;
    for (int b = tid; b < nbuck; b += 256) h[b] = 0;
    __syncthreads();
    int base = blockIdx.x * CHUNK;
    for (int i = tid; i < CHUNK; i += 256) {
        int e = base + i;
        if (e < E) atomicAdd(&h[col[e] >> 8], 1);
    }
    __syncthreads();
    for (int b = tid; b < nbuck; b += 256) hist[b * nchunk + blockIdx.x] = h[b];
}

// pass 2: bin edges into bucket-contiguous bbuf[(src,col)]
__global__ void k_bin(const int* __restrict__ ei, const int* __restrict__ histS,
                      const int* __restrict__ bsum2, int2* __restrict__ bbuf,
                      int nbuck, int nchunk, int E) {
    __shared__ int cur[512];
    int tid = threadIdx.x;
    for (int b = tid; b < nbuck; b += 256) {
        int idx = b * nchunk + blockIdx.x;
        cur[b] = histS[idx] + bsum2[idx >> 10];
    }
    __syncthreads();
    int base = blockIdx.x * CHUNK;
    for (int i = tid; i < CHUNK; i += 256) {
        int e = base + i;
        if (e < E) {
            int r = ei[e], c = ei[E + e];
            int pos = atomicAdd(&cur[c >> 8], 1);
            int2 p; p.x = r; p.y = c;
            bbuf[pos] = p;
        }
    }
}

// pass 3: exact per-col counts via per-bucket LDS histogram (no global atomics)
__global__ void k_cnt(const int2* __restrict__ bbuf, const int* __restrict__ histS,
                      const int* __restrict__ bsum2, int* __restrict__ cnt,
                      int nbuck, int nchunk, int N, int E) {
    __shared__ int h[256];
    int b = blockIdx.x, tid = threadIdx.x;
    h[tid] = 0;
    __syncthreads();
    int i0 = b * nchunk;
    int start = histS[i0] + bsum2[i0 >> 10];
    int end = E;
    if (b + 1 < nbuck) { int i1 = (b + 1) * nchunk; end = histS[i1] + bsum2[i1 >> 10]; }
    for (int i = start + tid; i < end; i += 256) atomicAdd(&h[bbuf[i].y & 255], 1);
    __syncthreads();
    int c = b * 256 + tid;
    if (c < N) cnt[c] = h[tid];
}

__global__ void k_fixup(const int* __restrict__ cnt, int* __restrict__ offs,
                        const int* __restrict__ bsum, float* __restrict__ dis,
                        int* __restrict__ cursor, int N) {
    int i = blockIdx.x * blockDim.x + threadIdx.x;
    if (i >= N) return;
    int o = offs[i] + bsum[i >> 10];
    offs[i] = o;
    cursor[i] = o;
    dis[i] = rsqrtf(1.0f + (float)cnt[i]);   // deg includes self-loop
}

// pass 4: exact placement; cursor window 1KB, epack window ~32KB -> L2-resident
__global__ void k_place(const int2* __restrict__ bbuf, const int* __restrict__ histS,
                        const int* __restrict__ bsum2, int* __restrict__ cursor,
                        const float* __restrict__ dis, int2* __restrict__ epack,
                        int nbuck, int nchunk, int E) {
    int b = blockIdx.x, tid = threadIdx.x;
    int i0 = b * nchunk;
    int start = histS[i0] + bsum2[i0 >> 10];
    int end = E;
    if (b + 1 < nbuck) { int i1 = (b + 1) * nchunk; end = histS[i1] + bsum2[i1 >> 10]; }
    for (int i = start + tid; i < end; i += 256) {
        int2 rc = bbuf[i];
        int pos = atomicAdd(&cursor[rc.y], 1);
        int2 p; p.x = rc.x; p.y = __float_as_int(dis[rc.x]);
        epack[pos] = p;
    }
}

// ---------------- W -> bf16 B-fragment pack ----------------
__global__ void k_prepW(const float* __restrict__ W, __bf16* __restrict__ Wfrag) {
    int idx = blockIdx.x * 256 + threadIdx.x;   // 0..16383
    int j = idx & 7, lane = (idx >> 3) & 63, kc = (idx >> 9) & 3, ft = idx >> 11;
    int k = kc * 32 + (lane >> 4) * 8 + j;
    int f = ft * 16 + (lane & 15);
    Wfrag[idx] = (__bf16)W[k * D + f];
}

// ---------------- MFMA GEMM: Y[N,128](bf16) = X[N,128] @ W ----------------
template <typename T>
__launch_bounds__(256)
__global__ void k_gemm(const T* __restrict__ X, const __bf16* __restrict__ Wfrag,
                       __bf16* __restrict__ Y, int N) {
    int tid = threadIdx.x;
    int w = tid >> 6, lane = tid & 63;
    int quad = lane >> 4, m = lane & 15;
    int nodeA = blockIdx.x * 64 + w * 16 + m;
    if (nodeA >= N) nodeA = N - 1;

    bf16x8 a[4];
#pragma unroll
    for (int kc = 0; kc < 4; kc++) {
        int kb = kc * 32 + quad * 8;
        if constexpr (sizeof(T) == 4) {
            f32x4 x0 = *(const f32x4*)(X + (size_t)nodeA * D + kb);
            f32x4 x1 = *(const f32x4*)(X + (size_t)nodeA * D + kb + 4);
#pragma unroll
            for (int j = 0; j < 4; j++) { a[kc][j] = (__bf16)x0[j]; a[kc][4 + j] = (__bf16)x1[j]; }
        } else {
            a[kc] = *(const bf16x8*)(X + (size_t)nodeA * D + kb);
        }
    }

    f32x4 d[8];
#pragma unroll
    for (int ft = 0; ft < 8; ft++) {
        d[ft] = (f32x4){0.f, 0.f, 0.f, 0.f};
#pragma unroll
        for (int kc = 0; kc < 4; kc++) {
            bf16x8 b = *(const bf16x8*)(Wfrag + (((ft << 2) | kc) * 64 + lane) * 8);
            d[ft] = __builtin_amdgcn_mfma_f32_16x16x32_bf16(a[kc], b, d[ft], 0, 0, 0);
        }
    }

#pragma unroll
    for (int r = 0; r < 4; r++) {
        int node = blockIdx.x * 64 + w * 16 + quad * 4 + r;
        if (node < N) {
#pragma unroll
            for (int ft = 0; ft < 8; ft++)
                Y[(size_t)node * D + ft * 16 + m] = (__bf16)d[ft][r];
        }
    }
}

// ---------------- CSR aggregation + bias + leaky ReLU (bf16 in/out) ----------------
__launch_bounds__(256)
__global__ void k_agg(const __bf16* __restrict__ H, __bf16* __restrict__ O,
                      const int* __restrict__ offs, const int* __restrict__ cnt,
                      const float* __restrict__ dis, const int2* __restrict__ epack,
                      const float* __restrict__ bias, int N) {
    int node = (blockIdx.x * 256 + threadIdx.x) >> 6;
    int lane = threadIdx.x & 63;
    if (node >= N) return;
    int start = offs[node];
    int len = cnt[node];
    float di = dis[node];
    bf16x2 h = *(const bf16x2*)(H + (size_t)node * D + lane * 2);
    float acc0 = (float)h[0] * di;       // self-loop (x di again at end -> di^2)
    float acc1 = (float)h[1] * di;

    for (int k0 = 0; k0 < len; k0 += 64) {
        int mm = len - k0; if (mm > 64) mm = 64;
        int2 ep = epack[start + k0 + (lane < mm ? lane : 0)];
        float epw = __int_as_float(ep.y);
        int j = 0;
        for (; j + 8 <= mm; j += 8) {
            int s[8]; float w[8]; bf16x2 hv[8];
#pragma unroll
            for (int u = 0; u < 8; u++) { s[u] = __shfl(ep.x, j + u); w[u] = __shfl(epw, j + u); }
#pragma unroll
            for (int u = 0; u < 8; u++) hv[u] = *(const bf16x2*)(H + (size_t)s[u] * D + lane * 2);
#pragma unroll
            for (int u = 0; u < 8; u++) { acc0 += w[u] * (float)hv[u][0]; acc1 += w[u] * (float)hv[u][1]; }
        }
        for (; j < mm; j++) {
            int s = __shfl(ep.x, j);
            float w = __shfl(epw, j);
            bf16x2 hv = *(const bf16x2*)(H + (size_t)s * D + lane * 2);
            acc0 += w * (float)hv[0]; acc1 += w * (float)hv[1];
        }
    }

    acc0 = acc0 * di + bias[lane * 2];
    acc1 = acc1 * di + bias[lane * 2 + 1];
    acc0 = acc0 >= 0.f ? acc0 : 0.01f * acc0;
    acc1 = acc1 >= 0.f ? acc1 : 0.01f * acc1;
    bf16x2 o; o[0] = (__bf16)acc0; o[1] = (__bf16)acc1;
    *(bf16x2*)(O + (size_t)node * D + lane * 2) = o;
}

// ---------------- pooling (bf16 in, fp32 accum) ----------------
__global__ void k_pool(const __bf16* __restrict__ H, const int* __restrict__ batch,
                       float* __restrict__ pooled, float* __restrict__ gcnt, int N) {
    int f = threadIdx.x;                 // 0..127
    int n0 = blockIdx.x * 128;
    if (n0 >= N) return;
    int n1 = min(n0 + 128, N);
    int cur = batch[n0];
    float acc = 0.f; int run = 0;
    for (int n = n0; n < n1; n++) {
        int g = batch[n];                // uniform across block -> no divergence
        if (g != cur) {
            atomicAdd(&pooled[cur * D + f], acc);
            if (f == 0) atomicAdd(&gcnt[cur], (float)run);
            acc = 0.f; run = 0; cur = g;
        }
        acc += (float)H[(size_t)n * D + f];
        run++;
    }
    atomicAdd(&pooled[cur * D + f], acc);
    if (f == 0) atomicAdd(&gcnt[cur], (float)run);
}

// ---------------- final FC ----------------
__global__ void k_fc(const float* __restrict__ pooled, const float* __restrict__ gcnt,
                     const float* __restrict__ fcW, const float* __restrict__ fcb,
                     float* __restrict__ out) {
    __shared__ float red[128];
    int g = blockIdx.x;
    int f = threadIdx.x;
    red[f] = pooled[g * D + f] * fcW[f];
    __syncthreads();
    for (int s = 64; s > 0; s >>= 1) {
        if (f < s) red[f] += red[f + s];
        __syncthreads();
    }
    if (f == 0) out[g] = red[0] / fmaxf(gcnt[g], 1.0f) + fcb[0];
}

extern "C" void kernel_launch(void* const* d_in, const int* in_sizes, int n_in,
                              void* d_out, int out_size, void* d_ws, size_t ws_size,
                              hipStream_t stream) {
    const float* x    = (const float*)d_in[0];
    const int*   ei   = (const int*)d_in[1];
    const int*   batch= (const int*)d_in[2];
    const float* W1   = (const float*)d_in[3];
    const float* b1   = (const float*)d_in[4];
    const float* W2   = (const float*)d_in[5];
    const float* b2   = (const float*)d_in[6];
    const float* fcW  = (const float*)d_in[7];
    const float* fcb  = (const float*)d_in[8];
    float* out = (float*)d_out;

    int N = in_sizes[0] / D;
    int E = in_sizes[1] / 2;

    int NBUCK  = (N + 255) >> 8;               // 391 for N=100000 (<=512)
    int NCHUNK = (E + CHUNK - 1) / CHUNK;      // 196 for E=1.6M
    int M = NBUCK * NCHUNK;                    // 76,636
    int mb = (M + 1023) / 1024;                // 75  (<=256)
    int nb = (N + 1023) / 1024;                // 98  (<=256)

    char* p = (char*)d_ws;
    auto alloc = [&](size_t bytes) { char* r = p; p += (bytes + 255) & ~(size_t)255; return r; };
    int*    cnt    = (int*)   alloc((size_t)N * 4);
    int*    offs   = (int*)   alloc((size_t)N * 4);
    int*    cursor = (int*)   alloc((size_t)N * 4);
    int*    bsum   = (int*)   alloc(256 * 4);
    int*    bsum2  = (int*)   alloc(256 * 4);
    float*  dis    = (float*) alloc((size_t)N * 4);
    int*    hist   = (int*)   alloc((size_t)M * 4);
    int*    histS  = (int*)   alloc((size_t)M * 4);
    int2*   bbuf   = (int2*)  alloc((size_t)E * 8);
    int2*   epack  = (int2*)  alloc((size_t)E * 8);
    __bf16* bufA   = (__bf16*)alloc((size_t)N * D * 2);
    __bf16* bufB   = (__bf16*)alloc((size_t)N * D * 2);
    __bf16* Wf1    = (__bf16*)alloc((size_t)D * D * 2);
    __bf16* Wf2    = (__bf16*)alloc((size_t)D * D * 2);
    float*  pooled = (float*) alloc((size_t)NUM_GRAPHS * D * 4);
    float*  gcnt   = (float*) alloc((size_t)NUM_GRAPHS * 4);

    hipMemsetAsync(pooled, 0, (size_t)NUM_GRAPHS * D * 4, stream);
    hipMemsetAsync(gcnt, 0, (size_t)NUM_GRAPHS * 4, stream);

    // CSR build (two-level counting sort; no random-line scatters)
    k_hist <<<NCHUNK, 256, 0, stream>>>(ei + E, hist, NBUCK, NCHUNK, E);
    k_scan1<<<mb, 256, 0, stream>>>(hist, histS, bsum2, M);
    k_scan2<<<1, 256, 0, stream>>>(bsum2, mb);
    k_bin  <<<NCHUNK, 256, 0, stream>>>(ei, histS, bsum2, bbuf, NBUCK, NCHUNK, E);
    k_cnt  <<<NBUCK, 256, 0, stream>>>(bbuf, histS, bsum2, cnt, NBUCK, NCHUNK, N, E);
    k_scan1<<<nb, 256, 0, stream>>>(cnt, offs, bsum, N);
    k_scan2<<<1, 256, 0, stream>>>(bsum, nb);
    k_fixup<<<(N + 255) / 256, 256, 0, stream>>>(cnt, offs, bsum, dis, cursor, N);
    k_place<<<NBUCK, 256, 0, stream>>>(bbuf, histS, bsum2, cursor, dis, epack, NBUCK, NCHUNK, E);

    k_prepW<<<64, 256, 0, stream>>>(W1, Wf1);
    k_prepW<<<64, 256, 0, stream>>>(W2, Wf2);

    int gblocks = (N + 63) / 64;

    // layer 1
    k_gemm<float><<<gblocks, 256, 0, stream>>>(x, Wf1, bufA, N);
    k_agg<<<(N + 3) / 4, 256, 0, stream>>>(bufA, bufB, offs, cnt, dis, epack, b1, N);
    // layer 2
    k_gemm<__bf16><<<gblocks, 256, 0, stream>>>(bufB, Wf2, bufA, N);
    k_agg<<<(N + 3) / 4, 256, 0, stream>>>(bufA, bufB, offs, cnt, dis, epack, b2, N);
    // pool + fc
    k_pool<<<(N + 127) / 128, 128, 0, stream>>>(bufB, batch, pooled, gcnt, N);
    k_fc<<<NUM_GRAPHS, 128, 0, stream>>>(pooled, gcnt, fcW, fcb, out);
}

// Round 5
// 358.584 us; speedup vs baseline: 2.9994x; 1.1065x over previous
//
#include <hip/hip_runtime.h>
#include <hip/hip_bf16.h>
#include <math.h>

#define D 128
#define NUM_GRAPHS 64
#define CHUNK 8192          // edges per binning block

typedef __bf16 bf16x8 __attribute__((ext_vector_type(8)));
typedef __bf16 bf16x2 __attribute__((ext_vector_type(2)));
typedef float f32x4 __attribute__((ext_vector_type(4)));

// ---------------- generic scan helpers (for the bucket-chunk table) ----------------
__global__ void k_scan1(const int* __restrict__ in, int* __restrict__ outv,
                        int* __restrict__ bsum, int N) {
    __shared__ int lds[256];
    int t = threadIdx.x;
    int base = blockIdx.x * 1024 + t * 4;
    int v[4]; int local = 0;
#pragma unroll
    for (int j = 0; j < 4; j++) { v[j] = (base + j < N) ? in[base + j] : 0; local += v[j]; }
    lds[t] = local;
    __syncthreads();
    for (int off = 1; off < 256; off <<= 1) {
        int x = (t >= off) ? lds[t - off] : 0;
        __syncthreads();
        lds[t] += x;
        __syncthreads();
    }
    int excl = lds[t] - local;
    if (t == 255) bsum[blockIdx.x] = lds[255];
    int run = excl;
#pragma unroll
    for (int j = 0; j < 4; j++) { if (base + j < N) outv[base + j] = run; run += v[j]; }
}

__global__ void k_scan2(int* __restrict__ bsum, int nb) {
    __shared__ int lds[256];
    int t = threadIdx.x;
    int v = (t < nb) ? bsum[t] : 0;
    lds[t] = v;
    __syncthreads();
    for (int off = 1; off < 256; off <<= 1) {
        int x = (t >= off) ? lds[t - off] : 0;
        __syncthreads();
        lds[t] += x;
        __syncthreads();
    }
    if (t < nb) bsum[t] = lds[t] - v;
}

// ---------------- CSR build: two-level counting sort ----------------
// pass 1: per-chunk histogram over coarse buckets (col>>8)
__global__ void k_hist(const int* __restrict__ col, int* __restrict__ hist,
                       int nbuck, int nchunk, int E) {
    __shared__ int h[512];
    int tid = threadIdx.x;
    for (int b = tid; b < nbuck; b += 256) h[b] = 0;
    __syncthreads();
    int base = blockIdx.x * CHUNK;
    for (int i = tid; i < CHUNK; i += 256) {
        int e = base + i;
        if (e < E) atomicAdd(&h[col[e] >> 8], 1);
    }
    __syncthreads();
    for (int b = tid; b < nbuck; b += 256) hist[b * nchunk + blockIdx.x] = h[b];
}

// pass 2: bin edges into bucket-contiguous packed (src | (col&255)<<17) records
__global__ void k_bin(const int* __restrict__ ei, const int* __restrict__ histS,
                      const int* __restrict__ bsum2, int* __restrict__ bbuf,
                      int nbuck, int nchunk, int E) {
    __shared__ int cur[512];
    int tid = threadIdx.x;
    for (int b = tid; b < nbuck; b += 256) {
        int idx = b * nchunk + blockIdx.x;
        cur[b] = histS[idx] + bsum2[idx >> 10];
    }
    __syncthreads();
    int base = blockIdx.x * CHUNK;
    for (int i = tid; i < CHUNK; i += 256) {
        int e = base + i;
        if (e < E) {
            int r = ei[e], c = ei[E + e];
            int pos = atomicAdd(&cur[c >> 8], 1);
            bbuf[pos] = r | ((c & 255) << 17);      // src fits 17 bits (N < 131072)
        }
    }
}

// pass 3: per-bucket exact CSR: LDS histogram + LDS scan + LDS cursors.
// Writes cnt/offs/dis per node and esrc (src only) — no global atomics.
__global__ void k_place(const int* __restrict__ bbuf, const int* __restrict__ histS,
                        const int* __restrict__ bsum2, int* __restrict__ esrc,
                        int* __restrict__ cnt, int* __restrict__ offs,
                        float* __restrict__ dis,
                        int nbuck, int nchunk, int N, int E) {
    __shared__ int h[256];
    __shared__ int sc[256];
    __shared__ int cur[256];
    int b = blockIdx.x, tid = threadIdx.x;
    int i0 = b * nchunk;
    int start = histS[i0] + bsum2[i0 >> 10];
    int end = E;
    if (b + 1 < nbuck) { int i1 = (b + 1) * nchunk; end = histS[i1] + bsum2[i1 >> 10]; }
    h[tid] = 0;
    __syncthreads();
    for (int i = start + tid; i < end; i += 256) atomicAdd(&h[(bbuf[i] >> 17) & 255], 1);
    __syncthreads();
    int local = h[tid];
    sc[tid] = local;
    __syncthreads();
    for (int off = 1; off < 256; off <<= 1) {
        int xv = (tid >= off) ? sc[tid - off] : 0;
        __syncthreads();
        sc[tid] += xv;
        __syncthreads();
    }
    int excl = sc[tid] - local;
    cur[tid] = start + excl;
    int c = b * 256 + tid;
    if (c < N) {
        cnt[c]  = local;
        offs[c] = start + excl;
        dis[c]  = rsqrtf(1.0f + (float)local);   // deg includes self-loop
    }
    __syncthreads();
    for (int i = start + tid; i < end; i += 256) {
        int p = bbuf[i];
        int pos = atomicAdd(&cur[(p >> 17) & 255], 1);
        esrc[pos] = p & 0x1FFFF;
    }
}

// ---------------- W -> bf16 B-fragment pack ----------------
__global__ void k_prepW(const float* __restrict__ W, __bf16* __restrict__ Wfrag) {
    int idx = blockIdx.x * 256 + threadIdx.x;   // 0..16383
    int j = idx & 7, lane = (idx >> 3) & 63, kc = (idx >> 9) & 3, ft = idx >> 11;
    int k = kc * 32 + (lane >> 4) * 8 + j;
    int f = ft * 16 + (lane & 15);
    Wfrag[idx] = (__bf16)W[k * D + f];
}

// ---------------- MFMA GEMM: Y[N,128](bf16) = dis .* (X[N,128] @ W) ----------------
// Prescaled output: Hs[n] = dis[n] * (X@W)[n], so the aggregation needs no
// per-edge weights (O = dis[i]*(sum Hs[j] + Hs[i]) + b).
template <typename T>
__launch_bounds__(256)
__global__ void k_gemm(const T* __restrict__ X, const __bf16* __restrict__ Wfrag,
                       const float* __restrict__ dis, __bf16* __restrict__ Y, int N) {
    int tid = threadIdx.x;
    int w = tid >> 6, lane = tid & 63;
    int quad = lane >> 4, m = lane & 15;
    int nodeA = blockIdx.x * 64 + w * 16 + m;
    if (nodeA >= N) nodeA = N - 1;

    bf16x8 a[4];
#pragma unroll
    for (int kc = 0; kc < 4; kc++) {
        int kb = kc * 32 + quad * 8;
        if constexpr (sizeof(T) == 4) {
            f32x4 x0 = *(const f32x4*)(X + (size_t)nodeA * D + kb);
            f32x4 x1 = *(const f32x4*)(X + (size_t)nodeA * D + kb + 4);
#pragma unroll
            for (int j = 0; j < 4; j++) { a[kc][j] = (__bf16)x0[j]; a[kc][4 + j] = (__bf16)x1[j]; }
        } else {
            a[kc] = *(const bf16x8*)(X + (size_t)nodeA * D + kb);
        }
    }

    f32x4 d[8];
#pragma unroll
    for (int ft = 0; ft < 8; ft++) {
        d[ft] = (f32x4){0.f, 0.f, 0.f, 0.f};
#pragma unroll
        for (int kc = 0; kc < 4; kc++) {
            bf16x8 b = *(const bf16x8*)(Wfrag + (((ft << 2) | kc) * 64 + lane) * 8);
            d[ft] = __builtin_amdgcn_mfma_f32_16x16x32_bf16(a[kc], b, d[ft], 0, 0, 0);
        }
    }

#pragma unroll
    for (int r = 0; r < 4; r++) {
        int node = blockIdx.x * 64 + w * 16 + quad * 4 + r;
        if (node < N) {
            float dv = dis[node];
#pragma unroll
            for (int ft = 0; ft < 8; ft++)
                Y[(size_t)node * D + ft * 16 + m] = (__bf16)(d[ft][r] * dv);
        }
    }
}

// ---------------- CSR aggregation + bias + leaky ReLU (bf16 in/out) ----------------
// Hs is prescaled by dis -> no per-edge weight. One wave per node; lane owns
// feats (2*lane, 2*lane+1). Edge src indices preloaded 64-at-a-time (coalesced
// int load + shfl broadcast); gather unrolled x16 for MLP depth.
__launch_bounds__(256)
__global__ void k_agg(const __bf16* __restrict__ Hs, __bf16* __restrict__ O,
                      const int* __restrict__ offs, const int* __restrict__ cnt,
                      const float* __restrict__ dis, const int* __restrict__ esrc,
                      const float* __restrict__ bias, int N) {
    int node = (blockIdx.x * 256 + threadIdx.x) >> 6;
    int lane = threadIdx.x & 63;
    if (node >= N) return;
    int start = offs[node];
    int len = cnt[node];
    float di = dis[node];
    bf16x2 h = *(const bf16x2*)(Hs + (size_t)node * D + lane * 2);
    float acc0 = (float)h[0];            // self-loop term (already dis-scaled)
    float acc1 = (float)h[1];

    for (int k0 = 0; k0 < len; k0 += 64) {
        int mm = len - k0; if (mm > 64) mm = 64;
        int ep = esrc[start + k0 + (lane < mm ? lane : 0)];
        int j = 0;
        for (; j + 16 <= mm; j += 16) {
            int s[16]; bf16x2 hv[16];
#pragma unroll
            for (int u = 0; u < 16; u++) s[u] = __shfl(ep, j + u);
#pragma unroll
            for (int u = 0; u < 16; u++) hv[u] = *(const bf16x2*)(Hs + (size_t)s[u] * D + lane * 2);
#pragma unroll
            for (int u = 0; u < 16; u++) { acc0 += (float)hv[u][0]; acc1 += (float)hv[u][1]; }
        }
        for (; j + 4 <= mm; j += 4) {
            int s[4]; bf16x2 hv[4];
#pragma unroll
            for (int u = 0; u < 4; u++) s[u] = __shfl(ep, j + u);
#pragma unroll
            for (int u = 0; u < 4; u++) hv[u] = *(const bf16x2*)(Hs + (size_t)s[u] * D + lane * 2);
#pragma unroll
            for (int u = 0; u < 4; u++) { acc0 += (float)hv[u][0]; acc1 += (float)hv[u][1]; }
        }
        for (; j < mm; j++) {
            int s = __shfl(ep, j);
            bf16x2 hv = *(const bf16x2*)(Hs + (size_t)s * D + lane * 2);
            acc0 += (float)hv[0]; acc1 += (float)hv[1];
        }
    }

    acc0 = acc0 * di + bias[lane * 2];
    acc1 = acc1 * di + bias[lane * 2 + 1];
    acc0 = acc0 >= 0.f ? acc0 : 0.01f * acc0;
    acc1 = acc1 >= 0.f ? acc1 : 0.01f * acc1;
    bf16x2 o; o[0] = (__bf16)acc0; o[1] = (__bf16)acc1;
    *(bf16x2*)(O + (size_t)node * D + lane * 2) = o;
}

// ---------------- pooling (bf16 in, fp32 accum) ----------------
__global__ void k_pool(const __bf16* __restrict__ H, const int* __restrict__ batch,
                       float* __restrict__ pooled, float* __restrict__ gcnt, int N) {
    int f = threadIdx.x;                 // 0..127
    int n0 = blockIdx.x * 128;
    if (n0 >= N) return;
    int n1 = min(n0 + 128, N);
    int cur = batch[n0];
    float acc = 0.f; int run = 0;
    for (int n = n0; n < n1; n++) {
        int g = batch[n];                // uniform across block -> no divergence
        if (g != cur) {
            atomicAdd(&pooled[cur * D + f], acc);
            if (f == 0) atomicAdd(&gcnt[cur], (float)run);
            acc = 0.f; run = 0; cur = g;
        }
        acc += (float)H[(size_t)n * D + f];
        run++;
    }
    atomicAdd(&pooled[cur * D + f], acc);
    if (f == 0) atomicAdd(&gcnt[cur], (float)run);
}

// ---------------- final FC ----------------
__global__ void k_fc(const float* __restrict__ pooled, const float* __restrict__ gcnt,
                     const float* __restrict__ fcW, const float* __restrict__ fcb,
                     float* __restrict__ out) {
    __shared__ float red[128];
    int g = blockIdx.x;
    int f = threadIdx.x;
    red[f] = pooled[g * D + f] * fcW[f];
    __syncthreads();
    for (int s = 64; s > 0; s >>= 1) {
        if (f < s) red[f] += red[f + s];
        __syncthreads();
    }
    if (f == 0) out[g] = red[0] / fmaxf(gcnt[g], 1.0f) + fcb[0];
}

extern "C" void kernel_launch(void* const* d_in, const int* in_sizes, int n_in,
                              void* d_out, int out_size, void* d_ws, size_t ws_size,
                              hipStream_t stream) {
    const float* x    = (const float*)d_in[0];
    const int*   ei   = (const int*)d_in[1];
    const int*   batch= (const int*)d_in[2];
    const float* W1   = (const float*)d_in[3];
    const float* b1   = (const float*)d_in[4];
    const float* W2   = (const float*)d_in[5];
    const float* b2   = (const float*)d_in[6];
    const float* fcW  = (const float*)d_in[7];
    const float* fcb  = (const float*)d_in[8];
    float* out = (float*)d_out;

    int N = in_sizes[0] / D;
    int E = in_sizes[1] / 2;

    int NBUCK  = (N + 255) >> 8;               // 391 for N=100000 (<=512)
    int NCHUNK = (E + CHUNK - 1) / CHUNK;      // 196 for E=1.6M
    int M = NBUCK * NCHUNK;                    // 76,636
    int mb = (M + 1023) / 1024;                // 75  (<=256)

    char* p = (char*)d_ws;
    auto alloc = [&](size_t bytes) { char* r = p; p += (bytes + 255) & ~(size_t)255; return r; };
    int*    cnt    = (int*)   alloc((size_t)N * 4);
    int*    offs   = (int*)   alloc((size_t)N * 4);
    int*    bsum2  = (int*)   alloc(256 * 4);
    float*  dis    = (float*) alloc((size_t)N * 4);
    int*    hist   = (int*)   alloc((size_t)M * 4);
    int*    histS  = (int*)   alloc((size_t)M * 4);
    int*    bbuf   = (int*)   alloc((size_t)E * 4);
    int*    esrc   = (int*)   alloc((size_t)E * 4);
    __bf16* bufA   = (__bf16*)alloc((size_t)N * D * 2);
    __bf16* bufB   = (__bf16*)alloc((size_t)N * D * 2);
    __bf16* Wf1    = (__bf16*)alloc((size_t)D * D * 2);
    __bf16* Wf2    = (__bf16*)alloc((size_t)D * D * 2);
    float*  pooled = (float*) alloc((size_t)NUM_GRAPHS * D * 4);
    float*  gcnt   = (float*) alloc((size_t)NUM_GRAPHS * 4);

    hipMemsetAsync(pooled, 0, (size_t)NUM_GRAPHS * D * 4, stream);
    hipMemsetAsync(gcnt, 0, (size_t)NUM_GRAPHS * 4, stream);

    // CSR build: hist -> scan -> bin -> per-bucket place (all-LDS cursors)
    k_hist <<<NCHUNK, 256, 0, stream>>>(ei + E, hist, NBUCK, NCHUNK, E);
    k_scan1<<<mb, 256, 0, stream>>>(hist, histS, bsum2, M);
    k_scan2<<<1, 256, 0, stream>>>(bsum2, mb);
    k_bin  <<<NCHUNK, 256, 0, stream>>>(ei, histS, bsum2, bbuf, NBUCK, NCHUNK, E);
    k_place<<<NBUCK, 256, 0, stream>>>(bbuf, histS, bsum2, esrc, cnt, offs, dis,
                                       NBUCK, NCHUNK, N, E);

    k_prepW<<<64, 256, 0, stream>>>(W1, Wf1);
    k_prepW<<<64, 256, 0, stream>>>(W2, Wf2);

    int gblocks = (N + 63) / 64;

    // layer 1 (GEMM output prescaled by dis)
    k_gemm<float><<<gblocks, 256, 0, stream>>>(x, Wf1, dis, bufA, N);
    k_agg<<<(N + 3) / 4, 256, 0, stream>>>(bufA, bufB, offs, cnt, dis, esrc, b1, N);
    // layer 2
    k_gemm<__bf16><<<gblocks, 256, 0, stream>>>(bufB, Wf2, dis, bufA, N);
    k_agg<<<(N + 3) / 4, 256, 0, stream>>>(bufA, bufB, offs, cnt, dis, esrc, b2, N);
    // pool + fc
    k_pool<<<(N + 127) / 128, 128, 0, stream>>>(bufB, batch, pooled, gcnt, N);
    k_fc<<<NUM_GRAPHS, 128, 0, stream>>>(pooled, gcnt, fcW, fcb, out);
}